// Round 3
// baseline (678.715 us; speedup 1.0000x reference)
//
#include <hip/hip_runtime.h>
#include <cstdint>
#include <cstddef>

#define NN 50000
#define EE 1600000
#define D  64
#define DE 16

typedef __attribute__((ext_vector_type(2))) float vf2;

__device__ __forceinline__ float bf2f(unsigned short u) {
    return __uint_as_float(((unsigned)u) << 16);
}
__device__ __forceinline__ unsigned short f2bf(float f) {
    unsigned u = __float_as_uint(f);
    unsigned r = u + 0x7FFFu + ((u >> 16) & 1u);   // RNE
    return (unsigned short)(r >> 16);
}

// ---------------- histogram of dst
__global__ __launch_bounds__(256) void k_hist(const int* dst, int* counts) {
    int e = blockIdx.x * 256 + threadIdx.x;
    if (e < EE) atomicAdd(&counts[dst[e]], 1);
}

// ---------------- 3-kernel exclusive scan over counts (chunks of 256)
__global__ __launch_bounds__(256) void k_scanA(const int* counts, int* bsum) {
    __shared__ int tmp[256];
    int t = threadIdx.x, i = blockIdx.x * 256 + t;
    tmp[t] = (i < NN) ? counts[i] : 0;
    __syncthreads();
    for (int off = 128; off; off >>= 1) {
        if (t < off) tmp[t] += tmp[t + off];
        __syncthreads();
    }
    if (t == 0) bsum[blockIdx.x] = tmp[0];
}

// scanB also computes wae = We@ae for both layers in otherwise-idle lanes
__global__ __launch_bounds__(256) void k_scanB(int* bsum, int nchunks,
                                               const float* We1, const float* ae1,
                                               const float* We2, const float* ae2,
                                               float* wae) {
    __shared__ int tmp[256];
    int t = threadIdx.x;
    int v = (t < nchunks) ? bsum[t] : 0;
    tmp[t] = v; __syncthreads();
    for (int off = 1; off < 256; off <<= 1) {
        int x = (t >= off) ? tmp[t - off] : 0;
        __syncthreads();
        tmp[t] += x;
        __syncthreads();
    }
    if (t < nchunks) bsum[t] = tmp[t] - v;   // exclusive
    if (t < 32) {
        const float* We = (t < 16) ? We1 : We2;
        const float* ae = (t < 16) ? ae1 : ae2;
        int k = t & 15;
        float acc = 0.f;
        #pragma unroll
        for (int c = 0; c < 64; c++) acc += We[k * 64 + c] * ae[c];
        wae[t] = acc;                         // [0..15]=layer1, [16..31]=layer2
    }
}

__global__ __launch_bounds__(256) void k_scanC(const int* counts, const int* bsumex,
                                               int* offsets, int* cursor) {
    __shared__ int tmp[256];
    int t = threadIdx.x, i = blockIdx.x * 256 + t;
    int v = (i < NN) ? counts[i] : 0;
    tmp[t] = v; __syncthreads();
    for (int off = 1; off < 256; off <<= 1) {
        int x = (t >= off) ? tmp[t - off] : 0;
        __syncthreads();
        tmp[t] += x;
        __syncthreads();
    }
    int excl = tmp[t] - v + bsumex[blockIdx.x];
    if (i < NN) { offsets[i] = excl; cursor[i] = excl; }
}

// ---------------- fused: layer-1 GEMM (blocks 0..1023) + edge scatter (rest).
// Scatter is now just {src,eid} int2 (ee recomputed in k_gat from staged ea row):
// removes the 102MB ea read + FMA work here and halves scattered write traffic.
// GEMM blocks first so the long-pole work starts immediately.
template<int IN_BF16>
__global__ __launch_bounds__(256, 4) void k_scatter_gemm(
        const int* src, const int* dst, int* cursor, int2* recs,
        const void* xin, const float* W, const float* a_s, const float* a_d,
        unsigned short* h, float* hs, float* hd) {
    int t = threadIdx.x;
    if (blockIdx.x < 1024) {
        int lane = t & 63;
        int wid0 = blockIdx.x * 4 + (t >> 6);        // 4096 waves total
        float Wcol[64];
        #pragma unroll
        for (int k = 0; k < 64; k++) Wcol[k] = W[k * 64 + lane];
        float asl = a_s[lane], adl = a_d[lane];
        for (int n0 = wid0; n0 < NN; n0 += 4096) {
            int n = __builtin_amdgcn_readfirstlane(n0);   // wave-uniform row address
            float acc = 0.f;
            if (IN_BF16) {
                const uint4* xr = (const uint4*)((const unsigned short*)xin + (size_t)n * 64);
                #pragma unroll
                for (int q = 0; q < 8; q++) {
                    uint4 u = xr[q];
                    unsigned uu[4] = {u.x, u.y, u.z, u.w};
                    #pragma unroll
                    for (int j = 0; j < 4; j++) {
                        acc += bf2f((unsigned short)(uu[j] & 0xFFFFu)) * Wcol[q * 8 + 2 * j];
                        acc += bf2f((unsigned short)(uu[j] >> 16))     * Wcol[q * 8 + 2 * j + 1];
                    }
                }
            } else {
                const float4* xr = (const float4*)((const float*)xin + (size_t)n * 64);
                #pragma unroll
                for (int q = 0; q < 16; q++) {
                    float4 u = xr[q];
                    acc += u.x * Wcol[4 * q]     + u.y * Wcol[4 * q + 1]
                         + u.z * Wcol[4 * q + 2] + u.w * Wcol[4 * q + 3];
                }
            }
            h[(size_t)n * 64 + lane] = f2bf(acc);
            float ps = acc * asl, pd = acc * adl;
            #pragma unroll
            for (int off = 32; off; off >>= 1) {
                ps += __shfl_xor(ps, off);
                pd += __shfl_xor(pd, off);
            }
            if (lane == 0) { hs[n] = ps; hd[n] = pd; }
        }
        return;
    }
    int e = (blockIdx.x - 1024) * 256 + t;
    if (e >= EE) return;
    int d = dst[e];
    int pos = atomicAdd(&cursor[d], 1);
    recs[pos] = make_int2(src[e], e);
}

// ---------------- standalone layer-2 GEMM
template<int IN_BF16>
__global__ __launch_bounds__(256, 4) void k_gemm(const void* xin, const float* W,
                                                 const float* a_s, const float* a_d,
                                                 unsigned short* h, float* hs, float* hd) {
    int t = threadIdx.x, lane = t & 63;
    int wid0 = blockIdx.x * 4 + (t >> 6);        // 4096 waves total
    float Wcol[64];
    #pragma unroll
    for (int k = 0; k < 64; k++) Wcol[k] = W[k * 64 + lane];
    float asl = a_s[lane], adl = a_d[lane];
    for (int n0 = wid0; n0 < NN; n0 += 4096) {
        int n = __builtin_amdgcn_readfirstlane(n0);
        float acc = 0.f;
        if (IN_BF16) {
            const uint4* xr = (const uint4*)((const unsigned short*)xin + (size_t)n * 64);
            #pragma unroll
            for (int q = 0; q < 8; q++) {
                uint4 u = xr[q];
                unsigned uu[4] = {u.x, u.y, u.z, u.w};
                #pragma unroll
                for (int j = 0; j < 4; j++) {
                    acc += bf2f((unsigned short)(uu[j] & 0xFFFFu)) * Wcol[q * 8 + 2 * j];
                    acc += bf2f((unsigned short)(uu[j] >> 16))     * Wcol[q * 8 + 2 * j + 1];
                }
            }
        } else {
            const float4* xr = (const float4*)((const float*)xin + (size_t)n * 64);
            #pragma unroll
            for (int q = 0; q < 16; q++) {
                float4 u = xr[q];
                acc += u.x * Wcol[4 * q]     + u.y * Wcol[4 * q + 1]
                     + u.z * Wcol[4 * q + 2] + u.w * Wcol[4 * q + 3];
            }
        }
        h[(size_t)n * 64 + lane] = f2bf(acc);
        float ps = acc * asl, pd = acc * adl;
        #pragma unroll
        for (int off = 32; off; off >>= 1) {
            ps += __shfl_xor(ps, off);
            pd += __shfl_xor(pd, off);
        }
        if (lane == 0) { hs[n] = ps; hd[n] = pd; }
    }
}

// ---------------- fused per-node GAT.
// R9: pass-2 was latency-bound (per-SIMD issue util ~24%; wave residency 16.6k cyc
// vs 1.3k cyc of issue — h[src] gather latency uncovered). Now pass 1 (lane=edge,
// full 64-lane MLP) stages EVERYTHING: ea row -> eal, full h[src] row (128B bf16,
// XOR-swizzled banks) -> hl, final att -> attl. Pass 2 is pure LDS + VALU with
// distance-1 LDS->reg prefetch: zero global loads, no long-latency chains.
// ee is recomputed in pass 1 from the staged ea row (recs shrank to int2).
// LDS/block = 16K(eal) + 32K(hl) + 1K(attl) = 50176B -> 3 blocks/CU.
template<int L2>   // L2: selects wae half; fp32 output
__global__ __launch_bounds__(256, 3) void k_gat(const int2* __restrict__ recs,
                                                const int* __restrict__ offsets,
                                                const int* __restrict__ counts,
                                                const float* __restrict__ hs,
                                                const float* __restrict__ hd,
                                                const unsigned short* __restrict__ h,
                                                const float* __restrict__ ea,
                                                const float* __restrict__ wae,
                                                const float* __restrict__ We,
                                                const float* __restrict__ b,
                                                void* __restrict__ outv) {
    __shared__ float4 eal[4][4][64];                 // [wave][k-quad][edge]
    __shared__ __align__(16) unsigned short hl[4][64][64];  // [wave][edge][ch], XOR-swizzled
    __shared__ float attl[4][64];                    // [wave][edge]
    int t = threadIdx.x, lane = t & 63, wv = t >> 6;
    int g = lane >> 4, cl = lane & 15;

    // W packed as k-pairs for the lane's 4 channels
    vf2 Wp[32];
    #pragma unroll
    for (int kp = 0; kp < 8; kp++) {
        float4 wa = *(const float4*)(We + (2 * kp) * 64 + 4 * cl);
        float4 wb = *(const float4*)(We + (2 * kp + 1) * 64 + 4 * cl);
        Wp[kp].x      = wa.x; Wp[kp].y      = wb.x;
        Wp[8 + kp].x  = wa.y; Wp[8 + kp].y  = wb.y;
        Wp[16 + kp].x = wa.z; Wp[16 + kp].y = wb.z;
        Wp[24 + kp].x = wa.w; Wp[24 + kp].y = wb.w;
    }
    // wae for this layer (broadcast loads, 16 regs; dead after pass 1)
    float waer[16];
    {
        const float4* wp4 = (const float4*)(wae + L2 * 16);
        float4 w0 = wp4[0], w1 = wp4[1], w2 = wp4[2], w3 = wp4[3];
        waer[0]=w0.x; waer[1]=w0.y; waer[2]=w0.z; waer[3]=w0.w;
        waer[4]=w1.x; waer[5]=w1.y; waer[6]=w1.z; waer[7]=w1.w;
        waer[8]=w2.x; waer[9]=w2.y; waer[10]=w2.z; waer[11]=w2.w;
        waer[12]=w3.x; waer[13]=w3.y; waer[14]=w3.z; waer[15]=w3.w;
    }

    int d = blockIdx.x * 4 + wv;           // grid is exactly NN/4
    int start = offsets[d];
    int deg = counts[d];

    if (deg == 0) {                        // isfinite -> 0, then bias + act
        if (g == 0) {
            float4 bl = *(const float4*)(b + 4 * cl);
            float o0 = (bl.x >= 0.f) ? bl.x : 0.01f * bl.x;
            float o1 = (bl.y >= 0.f) ? bl.y : 0.01f * bl.y;
            float o2 = (bl.z >= 0.f) ? bl.z : 0.01f * bl.z;
            float o3 = (bl.w >= 0.f) ? bl.w : 0.01f * bl.w;
            size_t oidx = (size_t)d * D + 4 * cl;
            if (L2) *(float4*)((float*)outv + oidx) = make_float4(o0, o1, o2, o3);
            else {
                ushort4 ov = {f2bf(o0), f2bf(o1), f2bf(o2), f2bf(o3)};
                *(ushort4*)((unsigned short*)outv + oidx) = ov;
            }
        }
        return;
    }

    float hdv = hd[d];
    bool fast = (deg <= 64);               // wave-uniform
    float m, invs;

    float ninf = -__builtin_inff();
    float a0 = ninf, a1 = ninf, a2 = ninf, a3 = ninf;

    if (fast) {
        // ---- pass 1: lane = edge; stage ea row + h row, compute logit (ee inline).
        float lg = ninf;
        if (lane < deg) {
            int2 r = recs[start + lane];
            int sr = r.x, eid = r.y;
            const float4* ep = (const float4*)(ea + (size_t)eid * DE);
            float4 q0 = ep[0], q1 = ep[1], q2 = ep[2], q3 = ep[3];
            const uint4* hp = (const uint4*)(h + (size_t)sr * D);
            float hsv = hs[sr];
            eal[wv][0][lane] = q0; eal[wv][1][lane] = q1;
            eal[wv][2][lane] = q2; eal[wv][3][lane] = q3;
            #pragma unroll
            for (int q = 0; q < 8; q++) {
                uint4 hvq = hp[q];
                *(uint4*)&hl[wv][lane][(8 * q) ^ ((lane & 7) << 3)] = hvq;
            }
            float ev[16] = {q0.x, q0.y, q0.z, q0.w, q1.x, q1.y, q1.z, q1.w,
                            q2.x, q2.y, q2.z, q2.w, q3.x, q3.y, q3.z, q3.w};
            float ee = 0.f;
            #pragma unroll
            for (int j = 0; j < 16; j++) ee += ev[j] * waer[j];
            lg = hsv + hdv + ee;
            lg = (lg >= 0.f) ? lg : 0.2f * lg;
        }

        // ---- softmax: max-reduce, one exp/lane, sum-reduce
        m = lg;
        #pragma unroll
        for (int off = 32; off; off >>= 1) m = fmaxf(m, __shfl_xor(m, off));
        float p = __expf(lg - m);          // lanes >= deg: lg=-inf -> p=0
        float s = p;
        #pragma unroll
        for (int off = 32; off; off >>= 1) s += __shfl_xor(s, off);
        invs = 1.0f / fmaxf(s, 1e-16f);
        if (lane < deg) attl[wv][lane] = p * invs;

        // ---- pass 2: pure LDS, distance-1 LDS->reg prefetch. No global loads.
        bool vC = (g < deg);
        int jC = vC ? g : 0;
        float4 qA[4];
        #pragma unroll
        for (int kq = 0; kq < 4; kq++) qA[kq] = eal[wv][kq][jC];
        ushort4 hC = *(const ushort4*)&hl[wv][jC][(4 * cl) ^ ((jC & 7) << 3)];
        float attC = attl[wv][jC];

        for (int i = 0; i < deg; i += 4) {
            int jn = i + 4 + g;
            bool vN = (jn < deg);
            int jN = vN ? jn : 0;
            float4 qB[4];
            #pragma unroll
            for (int kq = 0; kq < 4; kq++) qB[kq] = eal[wv][kq][jN];
            ushort4 hN = *(const ushort4*)&hl[wv][jN][(4 * cl) ^ ((jN & 7) << 3)];
            float attN = attl[wv][jN];

            vf2 acA = {0.f, 0.f}, acB = {0.f, 0.f}, acC2 = {0.f, 0.f}, acD = {0.f, 0.f};
            #pragma unroll
            for (int kq = 0; kq < 4; kq++) {
                float4 q = qA[kq];
                vf2 eA; eA.x = q.x; eA.y = q.y;
                vf2 eB; eB.x = q.z; eB.y = q.w;
                acA += eA * Wp[2 * kq];       acA += eB * Wp[2 * kq + 1];
                acB += eA * Wp[8 + 2 * kq];   acB += eB * Wp[8 + 2 * kq + 1];
                acC2 += eA * Wp[16 + 2 * kq]; acC2 += eB * Wp[16 + 2 * kq + 1];
                acD += eA * Wp[24 + 2 * kq];  acD += eB * Wp[24 + 2 * kq + 1];
            }
            float e0 = acA.x + acA.y, e1 = acB.x + acB.y;
            float e2 = acC2.x + acC2.y, e3 = acD.x + acD.y;
            float o0 = (bf2f(hC.x) + e0) * attC;
            float o1 = (bf2f(hC.y) + e1) * attC;
            float o2 = (bf2f(hC.z) + e2) * attC;
            float o3 = (bf2f(hC.w) + e3) * attC;
            if (vC) {
                a0 = fmaxf(a0, o0); a1 = fmaxf(a1, o1);
                a2 = fmaxf(a2, o2); a3 = fmaxf(a3, o3);
            }
            #pragma unroll
            for (int kq = 0; kq < 4; kq++) qA[kq] = qB[kq];
            hC = hN; attC = attN; vC = vN;
        }
    } else {
        // ---- slow path (deg > 64): online softmax + recompute-everything loop
        float mm = ninf, s = 0.f;
        for (int i = lane; i < deg; i += 64) {
            int2 r = recs[start + i];
            const float4* ep = (const float4*)(ea + (size_t)r.y * DE);
            float4 q0 = ep[0], q1 = ep[1], q2 = ep[2], q3 = ep[3];
            float ev[16] = {q0.x, q0.y, q0.z, q0.w, q1.x, q1.y, q1.z, q1.w,
                            q2.x, q2.y, q2.z, q2.w, q3.x, q3.y, q3.z, q3.w};
            float ee = 0.f;
            #pragma unroll
            for (int j = 0; j < 16; j++) ee += ev[j] * waer[j];
            float lg = hs[r.x] + hdv + ee;
            lg = (lg >= 0.f) ? lg : 0.2f * lg;
            float mn = fmaxf(mm, lg);
            s = ((mm == mn) ? s : s * __expf(mm - mn)) + __expf(lg - mn);
            mm = mn;
        }
        #pragma unroll
        for (int off = 32; off; off >>= 1) {
            float m2 = __shfl_xor(mm, off);
            float s2 = __shfl_xor(s, off);
            float mn = fmaxf(mm, m2);
            float sa = (mm == mn) ? s : s * __expf(mm - mn);
            float sb = (m2 == mn) ? s2 : s2 * __expf(m2 - mn);
            s = sa + sb;
            mm = mn;
        }
        m = mm;
        invs = 1.0f / fmaxf(s, 1e-16f);

        for (int i = 0; i < deg; i += 4) {
            int j = i + g;
            bool valid = (j < deg);
            int jc = valid ? j : 0;
            int2 r = recs[start + jc];
            const float4* ep = (const float4*)(ea + (size_t)r.y * DE);
            float4 q0 = ep[0], q1 = ep[1], q2 = ep[2], q3 = ep[3];
            float ev[16] = {q0.x, q0.y, q0.z, q0.w, q1.x, q1.y, q1.z, q1.w,
                            q2.x, q2.y, q2.z, q2.w, q3.x, q3.y, q3.z, q3.w};
            float ee = 0.f;
            #pragma unroll
            for (int j2 = 0; j2 < 16; j2++) ee += ev[j2] * waer[j2];
            float lg = hs[r.x] + hdv + ee;
            lg = (lg >= 0.f) ? lg : 0.2f * lg;
            float att = __expf(lg - m) * invs;
            ushort4 hv = *(const ushort4*)(h + (size_t)r.x * D + 4 * cl);
            float4 qs[4] = {q0, q1, q2, q3};
            vf2 acA = {0.f, 0.f}, acB = {0.f, 0.f}, acC2 = {0.f, 0.f}, acD = {0.f, 0.f};
            #pragma unroll
            for (int kq = 0; kq < 4; kq++) {
                float4 q = qs[kq];
                vf2 eA; eA.x = q.x; eA.y = q.y;
                vf2 eB; eB.x = q.z; eB.y = q.w;
                acA += eA * Wp[2 * kq];       acA += eB * Wp[2 * kq + 1];
                acB += eA * Wp[8 + 2 * kq];   acB += eB * Wp[8 + 2 * kq + 1];
                acC2 += eA * Wp[16 + 2 * kq]; acC2 += eB * Wp[16 + 2 * kq + 1];
                acD += eA * Wp[24 + 2 * kq];  acD += eB * Wp[24 + 2 * kq + 1];
            }
            float e0 = acA.x + acA.y, e1 = acB.x + acB.y;
            float e2 = acC2.x + acC2.y, e3 = acD.x + acD.y;
            float o0 = (bf2f(hv.x) + e0) * att;
            float o1 = (bf2f(hv.y) + e1) * att;
            float o2 = (bf2f(hv.z) + e2) * att;
            float o3 = (bf2f(hv.w) + e3) * att;
            if (valid) {
                a0 = fmaxf(a0, o0); a1 = fmaxf(a1, o1);
                a2 = fmaxf(a2, o2); a3 = fmaxf(a3, o3);
            }
        }
    }

    // combine the 4 groups (xor lanes 16, 32)
    #pragma unroll
    for (int off = 16; off <= 32; off <<= 1) {
        a0 = fmaxf(a0, __shfl_xor(a0, off));
        a1 = fmaxf(a1, __shfl_xor(a1, off));
        a2 = fmaxf(a2, __shfl_xor(a2, off));
        a3 = fmaxf(a3, __shfl_xor(a3, off));
    }

    if (g == 0) {
        float4 bl = *(const float4*)(b + 4 * cl);
        float o0 = a0 + bl.x, o1 = a1 + bl.y;
        float o2 = a2 + bl.z, o3 = a3 + bl.w;
        o0 = (o0 >= 0.f) ? o0 : 0.01f * o0;
        o1 = (o1 >= 0.f) ? o1 : 0.01f * o1;
        o2 = (o2 >= 0.f) ? o2 : 0.01f * o2;
        o3 = (o3 >= 0.f) ? o3 : 0.01f * o3;
        size_t oidx = (size_t)d * D + 4 * cl;
        if (L2) {
            *(float4*)((float*)outv + oidx) = make_float4(o0, o1, o2, o3);
        } else {
            ushort4 ov = {f2bf(o0), f2bf(o1), f2bf(o2), f2bf(o3)};
            *(ushort4*)((unsigned short*)outv + oidx) = ov;
        }
    }
}

extern "C" void kernel_launch(void* const* d_in, const int* in_sizes, int n_in,
                              void* d_out, int out_size, void* d_ws, size_t ws_size,
                              hipStream_t stream) {
    const float* X   = (const float*)d_in[0];
    const int*   eix = (const int*)d_in[1];
    const float* ea  = (const float*)d_in[2];
    const float* W1  = (const float*)d_in[3];
    const float* We1 = (const float*)d_in[4];
    const float* as1 = (const float*)d_in[5];
    const float* ad1 = (const float*)d_in[6];
    const float* ae1 = (const float*)d_in[7];
    const float* b1  = (const float*)d_in[8];
    const float* W2  = (const float*)d_in[9];
    const float* We2 = (const float*)d_in[10];
    const float* as2 = (const float*)d_in[11];
    const float* ad2 = (const float*)d_in[12];
    const float* ae2 = (const float*)d_in[13];
    const float* b2  = (const float*)d_in[14];

    const int* src = eix;
    const int* dst = eix + EE;

    // workspace carve — total ~26.8 MB
    char* w = (char*)d_ws;
    int2* recs = (int2*)w;               w += (size_t)EE * 8;          // 12.8 MB
    unsigned short* hA = (unsigned short*)w; w += (size_t)NN * D * 2;  // 6.4 MB (h1)
    unsigned short* hB = (unsigned short*)w; w += (size_t)NN * D * 2;  // 6.4 MB (c1 -> h2 in-place)
    float* hs = (float*)w;               w += (size_t)NN * 4;
    float* hd = (float*)w;               w += (size_t)NN * 4;
    int* counts = (int*)w;               w += (size_t)NN * 4;
    int* offsets = (int*)w;              w += (size_t)NN * 4;
    int* cursor = (int*)w;               w += (size_t)NN * 4;
    int* bsum = (int*)w;                 w += 256 * 4;
    float* wae = (float*)w;              w += 32 * 4;

    const int nchunks = (NN + 255) / 256;   // 196
    const int nsblk = (EE + 255) / 256;     // 6250

    hipMemsetAsync(counts, 0, (size_t)NN * 4, stream);
    k_hist<<<nsblk, 256, 0, stream>>>(dst, counts);
    k_scanA<<<nchunks, 256, 0, stream>>>(counts, bsum);
    k_scanB<<<1, 256, 0, stream>>>(bsum, nchunks, We1, ae1, We2, ae2, wae);
    k_scanC<<<nchunks, 256, 0, stream>>>(counts, bsum, offsets, cursor);

    // fused: layer-1 GEMM (1024 blocks) + scatter (6250 blocks)
    k_scatter_gemm<0><<<1024 + nsblk, 256, 0, stream>>>(src, dst, cursor, recs,
                                                        X, W1, as1, ad1, hA, hs, hd);
    k_gat<0><<<NN / 4, 256, 0, stream>>>(recs, offsets, counts, hs, hd, hA, ea,
                                         wae, We1, b1, hB);
    // layer 2
    k_gemm<1><<<1024, 256, 0, stream>>>(hB, W2, as2, ad2, hB, hs, hd);   // in-place
    k_gat<1><<<NN / 4, 256, 0, stream>>>(recs, offsets, counts, hs, hd, hB, ea,
                                         wae, We2, b2, (float*)d_out);
}

// Round 4
// 620.552 us; speedup vs baseline: 1.0937x; 1.0937x over previous
//
#include <hip/hip_runtime.h>
#include <cstdint>
#include <cstddef>

#define NN 50000
#define EE 1600000
#define D  64
#define DE 16

typedef __attribute__((ext_vector_type(2))) float vf2;

__device__ __forceinline__ float bf2f(unsigned short u) {
    return __uint_as_float(((unsigned)u) << 16);
}
__device__ __forceinline__ unsigned short f2bf(float f) {
    unsigned u = __float_as_uint(f);
    unsigned r = u + 0x7FFFu + ((u >> 16) & 1u);   // RNE
    return (unsigned short)(r >> 16);
}

// ---------------- histogram of dst
__global__ __launch_bounds__(256) void k_hist(const int* dst, int* counts) {
    int e = blockIdx.x * 256 + threadIdx.x;
    if (e < EE) atomicAdd(&counts[dst[e]], 1);
}

// ---------------- 3-kernel exclusive scan over counts (chunks of 256)
__global__ __launch_bounds__(256) void k_scanA(const int* counts, int* bsum) {
    __shared__ int tmp[256];
    int t = threadIdx.x, i = blockIdx.x * 256 + t;
    tmp[t] = (i < NN) ? counts[i] : 0;
    __syncthreads();
    for (int off = 128; off; off >>= 1) {
        if (t < off) tmp[t] += tmp[t + off];
        __syncthreads();
    }
    if (t == 0) bsum[blockIdx.x] = tmp[0];
}

// scanB also computes wae = We@ae for both layers in otherwise-idle lanes
__global__ __launch_bounds__(256) void k_scanB(int* bsum, int nchunks,
                                               const float* We1, const float* ae1,
                                               const float* We2, const float* ae2,
                                               float* wae) {
    __shared__ int tmp[256];
    int t = threadIdx.x;
    int v = (t < nchunks) ? bsum[t] : 0;
    tmp[t] = v; __syncthreads();
    for (int off = 1; off < 256; off <<= 1) {
        int x = (t >= off) ? tmp[t - off] : 0;
        __syncthreads();
        tmp[t] += x;
        __syncthreads();
    }
    if (t < nchunks) bsum[t] = tmp[t] - v;   // exclusive
    if (t < 32) {
        const float* We = (t < 16) ? We1 : We2;
        const float* ae = (t < 16) ? ae1 : ae2;
        int k = t & 15;
        float acc = 0.f;
        #pragma unroll
        for (int c = 0; c < 64; c++) acc += We[k * 64 + c] * ae[c];
        wae[t] = acc;                         // [0..15]=layer1, [16..31]=layer2
    }
}

__global__ __launch_bounds__(256) void k_scanC(const int* counts, const int* bsumex,
                                               int* offsets, int* cursor) {
    __shared__ int tmp[256];
    int t = threadIdx.x, i = blockIdx.x * 256 + t;
    int v = (i < NN) ? counts[i] : 0;
    tmp[t] = v; __syncthreads();
    for (int off = 1; off < 256; off <<= 1) {
        int x = (t >= off) ? tmp[t - off] : 0;
        __syncthreads();
        tmp[t] += x;
        __syncthreads();
    }
    int excl = tmp[t] - v + bsumex[blockIdx.x];
    if (i < NN) { offsets[i] = excl; cursor[i] = excl; }
}

// ---------------- scatter edges into dst-sorted {src, eid} records.
// R10: un-fused from gemm (the fusion's launch_bounds(256,4) halved scatter's
// occupancy and it's a pure latency chain -> 198us). Standalone again (8
// blocks/CU) + 8 edges/thread so 8 independent atomicAdd chains pipeline.
#define SC_ILP 8
__global__ __launch_bounds__(256) void k_scatter(const int* __restrict__ src,
                                                 const int* __restrict__ dst,
                                                 int* __restrict__ cursor,
                                                 int2* __restrict__ recs) {
    int t = threadIdx.x;
    int base = blockIdx.x * (256 * SC_ILP) + t;
    int dd[SC_ILP], ss[SC_ILP], pos[SC_ILP];
    bool v[SC_ILP];
    #pragma unroll
    for (int j = 0; j < SC_ILP; j++) {
        int e = base + j * 256;
        v[j] = (e < EE);
        int ec = v[j] ? e : 0;
        dd[j] = dst[ec];
        ss[j] = src[ec];
    }
    #pragma unroll
    for (int j = 0; j < SC_ILP; j++)
        if (v[j]) pos[j] = atomicAdd(&cursor[dd[j]], 1);
    #pragma unroll
    for (int j = 0; j < SC_ILP; j++)
        if (v[j]) recs[pos[j]] = make_int2(ss[j], base + j * 256);
}

// ---------------- per-layer: h = x@W, hs = h@a_s, hd = h@a_d
// W column in registers (64 VGPR/lane): __launch_bounds__(256,4) -> 128-VGPR budget.
template<int IN_BF16>
__global__ __launch_bounds__(256, 4) void k_gemm(const void* xin, const float* W,
                                                 const float* a_s, const float* a_d,
                                                 unsigned short* h, float* hs, float* hd) {
    int t = threadIdx.x, lane = t & 63;
    int wid0 = blockIdx.x * 4 + (t >> 6);        // 4096 waves total
    float Wcol[64];
    #pragma unroll
    for (int k = 0; k < 64; k++) Wcol[k] = W[k * 64 + lane];
    float asl = a_s[lane], adl = a_d[lane];
    for (int n0 = wid0; n0 < NN; n0 += 4096) {
        int n = __builtin_amdgcn_readfirstlane(n0);
        float acc = 0.f;
        if (IN_BF16) {
            const uint4* xr = (const uint4*)((const unsigned short*)xin + (size_t)n * 64);
            #pragma unroll
            for (int q = 0; q < 8; q++) {
                uint4 u = xr[q];
                unsigned uu[4] = {u.x, u.y, u.z, u.w};
                #pragma unroll
                for (int j = 0; j < 4; j++) {
                    acc += bf2f((unsigned short)(uu[j] & 0xFFFFu)) * Wcol[q * 8 + 2 * j];
                    acc += bf2f((unsigned short)(uu[j] >> 16))     * Wcol[q * 8 + 2 * j + 1];
                }
            }
        } else {
            const float4* xr = (const float4*)((const float*)xin + (size_t)n * 64);
            #pragma unroll
            for (int q = 0; q < 16; q++) {
                float4 u = xr[q];
                acc += u.x * Wcol[4 * q]     + u.y * Wcol[4 * q + 1]
                     + u.z * Wcol[4 * q + 2] + u.w * Wcol[4 * q + 3];
            }
        }
        h[(size_t)n * 64 + lane] = f2bf(acc);
        float ps = acc * asl, pd = acc * adl;
        #pragma unroll
        for (int off = 32; off; off >>= 1) {
            ps += __shfl_xor(ps, off);
            pd += __shfl_xor(pd, off);
        }
        if (lane == 0) { hs[n] = ps; hd[n] = pd; }
    }
}

// ---------------- fused per-node GAT.
// R9 design (kept): pass 1 (lane=edge, full 64-lane MLP) stages EVERYTHING:
// ea row -> eal, full h[src] row (128B bf16, XOR-swizzled banks) -> hl,
// final att -> attl. Pass 2 is pure LDS + VALU with distance-1 LDS->reg
// prefetch: zero global loads, no long-latency chains. ee recomputed in pass 1
// from the staged ea row (recs are int2). LDS/block ~50KB -> 3 blocks/CU.
template<int L2>   // L2: selects wae half; fp32 output
__global__ __launch_bounds__(256, 3) void k_gat(const int2* __restrict__ recs,
                                                const int* __restrict__ offsets,
                                                const int* __restrict__ counts,
                                                const float* __restrict__ hs,
                                                const float* __restrict__ hd,
                                                const unsigned short* __restrict__ h,
                                                const float* __restrict__ ea,
                                                const float* __restrict__ wae,
                                                const float* __restrict__ We,
                                                const float* __restrict__ b,
                                                void* __restrict__ outv) {
    __shared__ float4 eal[4][4][64];                 // [wave][k-quad][edge]
    __shared__ __align__(16) unsigned short hl[4][64][64];  // [wave][edge][ch], XOR-swizzled
    __shared__ float attl[4][64];                    // [wave][edge]
    int t = threadIdx.x, lane = t & 63, wv = t >> 6;
    int g = lane >> 4, cl = lane & 15;

    // W packed as k-pairs for the lane's 4 channels
    vf2 Wp[32];
    #pragma unroll
    for (int kp = 0; kp < 8; kp++) {
        float4 wa = *(const float4*)(We + (2 * kp) * 64 + 4 * cl);
        float4 wb = *(const float4*)(We + (2 * kp + 1) * 64 + 4 * cl);
        Wp[kp].x      = wa.x; Wp[kp].y      = wb.x;
        Wp[8 + kp].x  = wa.y; Wp[8 + kp].y  = wb.y;
        Wp[16 + kp].x = wa.z; Wp[16 + kp].y = wb.z;
        Wp[24 + kp].x = wa.w; Wp[24 + kp].y = wb.w;
    }
    // wae for this layer (broadcast loads, 16 regs; dead after pass 1)
    float waer[16];
    {
        const float4* wp4 = (const float4*)(wae + L2 * 16);
        float4 w0 = wp4[0], w1 = wp4[1], w2 = wp4[2], w3 = wp4[3];
        waer[0]=w0.x; waer[1]=w0.y; waer[2]=w0.z; waer[3]=w0.w;
        waer[4]=w1.x; waer[5]=w1.y; waer[6]=w1.z; waer[7]=w1.w;
        waer[8]=w2.x; waer[9]=w2.y; waer[10]=w2.z; waer[11]=w2.w;
        waer[12]=w3.x; waer[13]=w3.y; waer[14]=w3.z; waer[15]=w3.w;
    }

    int d = blockIdx.x * 4 + wv;           // grid is exactly NN/4
    int start = offsets[d];
    int deg = counts[d];

    if (deg == 0) {                        // isfinite -> 0, then bias + act
        if (g == 0) {
            float4 bl = *(const float4*)(b + 4 * cl);
            float o0 = (bl.x >= 0.f) ? bl.x : 0.01f * bl.x;
            float o1 = (bl.y >= 0.f) ? bl.y : 0.01f * bl.y;
            float o2 = (bl.z >= 0.f) ? bl.z : 0.01f * bl.z;
            float o3 = (bl.w >= 0.f) ? bl.w : 0.01f * bl.w;
            size_t oidx = (size_t)d * D + 4 * cl;
            if (L2) *(float4*)((float*)outv + oidx) = make_float4(o0, o1, o2, o3);
            else {
                ushort4 ov = {f2bf(o0), f2bf(o1), f2bf(o2), f2bf(o3)};
                *(ushort4*)((unsigned short*)outv + oidx) = ov;
            }
        }
        return;
    }

    float hdv = hd[d];
    bool fast = (deg <= 64);               // wave-uniform
    float m, invs;

    float ninf = -__builtin_inff();
    float a0 = ninf, a1 = ninf, a2 = ninf, a3 = ninf;

    if (fast) {
        // ---- pass 1: lane = edge; stage ea row + h row, compute logit (ee inline).
        float lg = ninf;
        if (lane < deg) {
            int2 r = recs[start + lane];
            int sr = r.x, eid = r.y;
            const float4* ep = (const float4*)(ea + (size_t)eid * DE);
            float4 q0 = ep[0], q1 = ep[1], q2 = ep[2], q3 = ep[3];
            const uint4* hp = (const uint4*)(h + (size_t)sr * D);
            float hsv = hs[sr];
            eal[wv][0][lane] = q0; eal[wv][1][lane] = q1;
            eal[wv][2][lane] = q2; eal[wv][3][lane] = q3;
            #pragma unroll
            for (int q = 0; q < 8; q++) {
                uint4 hvq = hp[q];
                *(uint4*)&hl[wv][lane][(8 * q) ^ ((lane & 7) << 3)] = hvq;
            }
            float ev[16] = {q0.x, q0.y, q0.z, q0.w, q1.x, q1.y, q1.z, q1.w,
                            q2.x, q2.y, q2.z, q2.w, q3.x, q3.y, q3.z, q3.w};
            float ee = 0.f;
            #pragma unroll
            for (int j = 0; j < 16; j++) ee += ev[j] * waer[j];
            lg = hsv + hdv + ee;
            lg = (lg >= 0.f) ? lg : 0.2f * lg;
        }

        // ---- softmax: max-reduce, one exp/lane, sum-reduce
        m = lg;
        #pragma unroll
        for (int off = 32; off; off >>= 1) m = fmaxf(m, __shfl_xor(m, off));
        float p = __expf(lg - m);          // lanes >= deg: lg=-inf -> p=0
        float s = p;
        #pragma unroll
        for (int off = 32; off; off >>= 1) s += __shfl_xor(s, off);
        invs = 1.0f / fmaxf(s, 1e-16f);
        if (lane < deg) attl[wv][lane] = p * invs;

        // ---- pass 2: pure LDS, distance-1 LDS->reg prefetch. No global loads.
        bool vC = (g < deg);
        int jC = vC ? g : 0;
        float4 qA[4];
        #pragma unroll
        for (int kq = 0; kq < 4; kq++) qA[kq] = eal[wv][kq][jC];
        ushort4 hC = *(const ushort4*)&hl[wv][jC][(4 * cl) ^ ((jC & 7) << 3)];
        float attC = attl[wv][jC];

        for (int i = 0; i < deg; i += 4) {
            int jn = i + 4 + g;
            bool vN = (jn < deg);
            int jN = vN ? jn : 0;
            float4 qB[4];
            #pragma unroll
            for (int kq = 0; kq < 4; kq++) qB[kq] = eal[wv][kq][jN];
            ushort4 hN = *(const ushort4*)&hl[wv][jN][(4 * cl) ^ ((jN & 7) << 3)];
            float attN = attl[wv][jN];

            vf2 acA = {0.f, 0.f}, acB = {0.f, 0.f}, acC2 = {0.f, 0.f}, acD = {0.f, 0.f};
            #pragma unroll
            for (int kq = 0; kq < 4; kq++) {
                float4 q = qA[kq];
                vf2 eA; eA.x = q.x; eA.y = q.y;
                vf2 eB; eB.x = q.z; eB.y = q.w;
                acA += eA * Wp[2 * kq];       acA += eB * Wp[2 * kq + 1];
                acB += eA * Wp[8 + 2 * kq];   acB += eB * Wp[8 + 2 * kq + 1];
                acC2 += eA * Wp[16 + 2 * kq]; acC2 += eB * Wp[16 + 2 * kq + 1];
                acD += eA * Wp[24 + 2 * kq];  acD += eB * Wp[24 + 2 * kq + 1];
            }
            float e0 = acA.x + acA.y, e1 = acB.x + acB.y;
            float e2 = acC2.x + acC2.y, e3 = acD.x + acD.y;
            float o0 = (bf2f(hC.x) + e0) * attC;
            float o1 = (bf2f(hC.y) + e1) * attC;
            float o2 = (bf2f(hC.z) + e2) * attC;
            float o3 = (bf2f(hC.w) + e3) * attC;
            if (vC) {
                a0 = fmaxf(a0, o0); a1 = fmaxf(a1, o1);
                a2 = fmaxf(a2, o2); a3 = fmaxf(a3, o3);
            }
            #pragma unroll
            for (int kq = 0; kq < 4; kq++) qA[kq] = qB[kq];
            hC = hN; attC = attN; vC = vN;
        }
    } else {
        // ---- slow path (deg > 64): online softmax + recompute-everything loop
        float mm = ninf, s = 0.f;
        for (int i = lane; i < deg; i += 64) {
            int2 r = recs[start + i];
            const float4* ep = (const float4*)(ea + (size_t)r.y * DE);
            float4 q0 = ep[0], q1 = ep[1], q2 = ep[2], q3 = ep[3];
            float ev[16] = {q0.x, q0.y, q0.z, q0.w, q1.x, q1.y, q1.z, q1.w,
                            q2.x, q2.y, q2.z, q2.w, q3.x, q3.y, q3.z, q3.w};
            float ee = 0.f;
            #pragma unroll
            for (int j = 0; j < 16; j++) ee += ev[j] * waer[j];
            float lg = hs[r.x] + hdv + ee;
            lg = (lg >= 0.f) ? lg : 0.2f * lg;
            float mn = fmaxf(mm, lg);
            s = ((mm == mn) ? s : s * __expf(mm - mn)) + __expf(lg - mn);
            mm = mn;
        }
        #pragma unroll
        for (int off = 32; off; off >>= 1) {
            float m2 = __shfl_xor(mm, off);
            float s2 = __shfl_xor(s, off);
            float mn = fmaxf(mm, m2);
            float sa = (mm == mn) ? s : s * __expf(mm - mn);
            float sb = (m2 == mn) ? s2 : s2 * __expf(m2 - mn);
            s = sa + sb;
            mm = mn;
        }
        m = mm;
        invs = 1.0f / fmaxf(s, 1e-16f);

        for (int i = 0; i < deg; i += 4) {
            int j = i + g;
            bool valid = (j < deg);
            int jc = valid ? j : 0;
            int2 r = recs[start + jc];
            const float4* ep = (const float4*)(ea + (size_t)r.y * DE);
            float4 q0 = ep[0], q1 = ep[1], q2 = ep[2], q3 = ep[3];
            float ev[16] = {q0.x, q0.y, q0.z, q0.w, q1.x, q1.y, q1.z, q1.w,
                            q2.x, q2.y, q2.z, q2.w, q3.x, q3.y, q3.z, q3.w};
            float ee = 0.f;
            #pragma unroll
            for (int j2 = 0; j2 < 16; j2++) ee += ev[j2] * waer[j2];
            float lg = hs[r.x] + hdv + ee;
            lg = (lg >= 0.f) ? lg : 0.2f * lg;
            float att = __expf(lg - m) * invs;
            ushort4 hv = *(const ushort4*)(h + (size_t)r.x * D + 4 * cl);
            float4 qs[4] = {q0, q1, q2, q3};
            vf2 acA = {0.f, 0.f}, acB = {0.f, 0.f}, acC2 = {0.f, 0.f}, acD = {0.f, 0.f};
            #pragma unroll
            for (int kq = 0; kq < 4; kq++) {
                float4 q = qs[kq];
                vf2 eA; eA.x = q.x; eA.y = q.y;
                vf2 eB; eB.x = q.z; eB.y = q.w;
                acA += eA * Wp[2 * kq];       acA += eB * Wp[2 * kq + 1];
                acB += eA * Wp[8 + 2 * kq];   acB += eB * Wp[8 + 2 * kq + 1];
                acC2 += eA * Wp[16 + 2 * kq]; acC2 += eB * Wp[16 + 2 * kq + 1];
                acD += eA * Wp[24 + 2 * kq];  acD += eB * Wp[24 + 2 * kq + 1];
            }
            float e0 = acA.x + acA.y, e1 = acB.x + acB.y;
            float e2 = acC2.x + acC2.y, e3 = acD.x + acD.y;
            float o0 = (bf2f(hv.x) + e0) * att;
            float o1 = (bf2f(hv.y) + e1) * att;
            float o2 = (bf2f(hv.z) + e2) * att;
            float o3 = (bf2f(hv.w) + e3) * att;
            if (valid) {
                a0 = fmaxf(a0, o0); a1 = fmaxf(a1, o1);
                a2 = fmaxf(a2, o2); a3 = fmaxf(a3, o3);
            }
        }
    }

    // combine the 4 groups (xor lanes 16, 32)
    #pragma unroll
    for (int off = 16; off <= 32; off <<= 1) {
        a0 = fmaxf(a0, __shfl_xor(a0, off));
        a1 = fmaxf(a1, __shfl_xor(a1, off));
        a2 = fmaxf(a2, __shfl_xor(a2, off));
        a3 = fmaxf(a3, __shfl_xor(a3, off));
    }

    if (g == 0) {
        float4 bl = *(const float4*)(b + 4 * cl);
        float o0 = a0 + bl.x, o1 = a1 + bl.y;
        float o2 = a2 + bl.z, o3 = a3 + bl.w;
        o0 = (o0 >= 0.f) ? o0 : 0.01f * o0;
        o1 = (o1 >= 0.f) ? o1 : 0.01f * o1;
        o2 = (o2 >= 0.f) ? o2 : 0.01f * o2;
        o3 = (o3 >= 0.f) ? o3 : 0.01f * o3;
        size_t oidx = (size_t)d * D + 4 * cl;
        if (L2) {
            *(float4*)((float*)outv + oidx) = make_float4(o0, o1, o2, o3);
        } else {
            ushort4 ov = {f2bf(o0), f2bf(o1), f2bf(o2), f2bf(o3)};
            *(ushort4*)((unsigned short*)outv + oidx) = ov;
        }
    }
}

extern "C" void kernel_launch(void* const* d_in, const int* in_sizes, int n_in,
                              void* d_out, int out_size, void* d_ws, size_t ws_size,
                              hipStream_t stream) {
    const float* X   = (const float*)d_in[0];
    const int*   eix = (const int*)d_in[1];
    const float* ea  = (const float*)d_in[2];
    const float* W1  = (const float*)d_in[3];
    const float* We1 = (const float*)d_in[4];
    const float* as1 = (const float*)d_in[5];
    const float* ad1 = (const float*)d_in[6];
    const float* ae1 = (const float*)d_in[7];
    const float* b1  = (const float*)d_in[8];
    const float* W2  = (const float*)d_in[9];
    const float* We2 = (const float*)d_in[10];
    const float* as2 = (const float*)d_in[11];
    const float* ad2 = (const float*)d_in[12];
    const float* ae2 = (const float*)d_in[13];
    const float* b2  = (const float*)d_in[14];

    const int* src = eix;
    const int* dst = eix + EE;

    // workspace carve — total ~26.8 MB
    char* w = (char*)d_ws;
    int2* recs = (int2*)w;               w += (size_t)EE * 8;          // 12.8 MB
    unsigned short* hA = (unsigned short*)w; w += (size_t)NN * D * 2;  // 6.4 MB (h1)
    unsigned short* hB = (unsigned short*)w; w += (size_t)NN * D * 2;  // 6.4 MB (c1 -> h2 in-place)
    float* hs = (float*)w;               w += (size_t)NN * 4;
    float* hd = (float*)w;               w += (size_t)NN * 4;
    int* counts = (int*)w;               w += (size_t)NN * 4;
    int* offsets = (int*)w;              w += (size_t)NN * 4;
    int* cursor = (int*)w;               w += (size_t)NN * 4;
    int* bsum = (int*)w;                 w += 256 * 4;
    float* wae = (float*)w;              w += 32 * 4;

    const int nchunks = (NN + 255) / 256;   // 196
    const int nsblk = (EE + 2047) / 2048;   // 782 (scatter, 8 edges/thread)

    hipMemsetAsync(counts, 0, (size_t)NN * 4, stream);
    k_hist<<<(EE + 255) / 256, 256, 0, stream>>>(dst, counts);
    k_scanA<<<nchunks, 256, 0, stream>>>(counts, bsum);
    k_scanB<<<1, 256, 0, stream>>>(bsum, nchunks, We1, ae1, We2, ae2, wae);
    k_scanC<<<nchunks, 256, 0, stream>>>(counts, bsum, offsets, cursor);
    k_scatter<<<nsblk, 256, 0, stream>>>(src, dst, cursor, recs);

    // layer 1
    k_gemm<0><<<1024, 256, 0, stream>>>(X, W1, as1, ad1, hA, hs, hd);
    k_gat<0><<<NN / 4, 256, 0, stream>>>(recs, offsets, counts, hs, hd, hA, ea,
                                         wae, We1, b1, hB);
    // layer 2
    k_gemm<1><<<1024, 256, 0, stream>>>(hB, W2, as2, ad2, hB, hs, hd);   // in-place
    k_gat<1><<<NN / 4, 256, 0, stream>>>(recs, offsets, counts, hs, hd, hB, ea,
                                         wae, We2, b2, (float*)d_out);
}

// Round 5
// 614.743 us; speedup vs baseline: 1.1041x; 1.0095x over previous
//
#include <hip/hip_runtime.h>
#include <cstdint>
#include <cstddef>

#define NN 50000
#define EE 1600000
#define D  64
#define DE 16

typedef __attribute__((ext_vector_type(2))) float vf2;

__device__ __forceinline__ float bf2f(unsigned short u) {
    return __uint_as_float(((unsigned)u) << 16);
}
__device__ __forceinline__ unsigned short f2bf(float f) {
    unsigned u = __float_as_uint(f);
    unsigned r = u + 0x7FFFu + ((u >> 16) & 1u);   // RNE
    return (unsigned short)(r >> 16);
}

// ---------------- histogram of dst (R11: 4-edge ILP -> 4 atomic chains in flight)
#define HI_ILP 4
__global__ __launch_bounds__(256) void k_hist(const int* __restrict__ dst,
                                              int* __restrict__ counts) {
    int base = blockIdx.x * (256 * HI_ILP) + threadIdx.x;
    int dd[HI_ILP]; bool v[HI_ILP];
    #pragma unroll
    for (int j = 0; j < HI_ILP; j++) {
        int e = base + j * 256;
        v[j] = (e < EE);
        dd[j] = dst[v[j] ? e : 0];
    }
    #pragma unroll
    for (int j = 0; j < HI_ILP; j++)
        if (v[j]) atomicAdd(&counts[dd[j]], 1);
}

// ---------------- 3-kernel exclusive scan over counts (chunks of 256)
__global__ __launch_bounds__(256) void k_scanA(const int* counts, int* bsum) {
    __shared__ int tmp[256];
    int t = threadIdx.x, i = blockIdx.x * 256 + t;
    tmp[t] = (i < NN) ? counts[i] : 0;
    __syncthreads();
    for (int off = 128; off; off >>= 1) {
        if (t < off) tmp[t] += tmp[t + off];
        __syncthreads();
    }
    if (t == 0) bsum[blockIdx.x] = tmp[0];
}

// scanB also computes wae = We@ae for both layers in otherwise-idle lanes
__global__ __launch_bounds__(256) void k_scanB(int* bsum, int nchunks,
                                               const float* We1, const float* ae1,
                                               const float* We2, const float* ae2,
                                               float* wae) {
    __shared__ int tmp[256];
    int t = threadIdx.x;
    int v = (t < nchunks) ? bsum[t] : 0;
    tmp[t] = v; __syncthreads();
    for (int off = 1; off < 256; off <<= 1) {
        int x = (t >= off) ? tmp[t - off] : 0;
        __syncthreads();
        tmp[t] += x;
        __syncthreads();
    }
    if (t < nchunks) bsum[t] = tmp[t] - v;   // exclusive
    if (t < 32) {
        const float* We = (t < 16) ? We1 : We2;
        const float* ae = (t < 16) ? ae1 : ae2;
        int k = t & 15;
        float acc = 0.f;
        #pragma unroll
        for (int c = 0; c < 64; c++) acc += We[k * 64 + c] * ae[c];
        wae[t] = acc;                         // [0..15]=layer1, [16..31]=layer2
    }
}

__global__ __launch_bounds__(256) void k_scanC(const int* counts, const int* bsumex,
                                               int* offsets, int* cursor) {
    __shared__ int tmp[256];
    int t = threadIdx.x, i = blockIdx.x * 256 + t;
    int v = (i < NN) ? counts[i] : 0;
    tmp[t] = v; __syncthreads();
    for (int off = 1; off < 256; off <<= 1) {
        int x = (t >= off) ? tmp[t - off] : 0;
        __syncthreads();
        tmp[t] += x;
        __syncthreads();
    }
    int excl = tmp[t] - v + bsumex[blockIdx.x];
    if (i < NN) { offsets[i] = excl; cursor[i] = excl; }
}

// ---------------- scatter edges into dst-sorted {src, eid} records.
// Standalone (default occupancy) + 8 edges/thread: 8 independent atomic chains.
#define SC_ILP 8
__global__ __launch_bounds__(256) void k_scatter(const int* __restrict__ src,
                                                 const int* __restrict__ dst,
                                                 int* __restrict__ cursor,
                                                 int2* __restrict__ recs) {
    int t = threadIdx.x;
    int base = blockIdx.x * (256 * SC_ILP) + t;
    int dd[SC_ILP], ss[SC_ILP], pos[SC_ILP];
    bool v[SC_ILP];
    #pragma unroll
    for (int j = 0; j < SC_ILP; j++) {
        int e = base + j * 256;
        v[j] = (e < EE);
        int ec = v[j] ? e : 0;
        dd[j] = dst[ec];
        ss[j] = src[ec];
    }
    #pragma unroll
    for (int j = 0; j < SC_ILP; j++)
        if (v[j]) pos[j] = atomicAdd(&cursor[dd[j]], 1);
    #pragma unroll
    for (int j = 0; j < SC_ILP; j++)
        if (v[j]) recs[pos[j]] = make_int2(ss[j], base + j * 256);
}

// ---------------- per-layer: h = x@W, hs = h@a_s, hd = h@a_d
// W column in registers (64 VGPR/lane): __launch_bounds__(256,4) -> 128-VGPR budget.
template<int IN_BF16>
__global__ __launch_bounds__(256, 4) void k_gemm(const void* xin, const float* W,
                                                 const float* a_s, const float* a_d,
                                                 unsigned short* h, float* hs, float* hd) {
    int t = threadIdx.x, lane = t & 63;
    int wid0 = blockIdx.x * 4 + (t >> 6);        // 4096 waves total
    float Wcol[64];
    #pragma unroll
    for (int k = 0; k < 64; k++) Wcol[k] = W[k * 64 + lane];
    float asl = a_s[lane], adl = a_d[lane];
    for (int n0 = wid0; n0 < NN; n0 += 4096) {
        int n = __builtin_amdgcn_readfirstlane(n0);
        float acc = 0.f;
        if (IN_BF16) {
            const uint4* xr = (const uint4*)((const unsigned short*)xin + (size_t)n * 64);
            #pragma unroll
            for (int q = 0; q < 8; q++) {
                uint4 u = xr[q];
                unsigned uu[4] = {u.x, u.y, u.z, u.w};
                #pragma unroll
                for (int j = 0; j < 4; j++) {
                    acc += bf2f((unsigned short)(uu[j] & 0xFFFFu)) * Wcol[q * 8 + 2 * j];
                    acc += bf2f((unsigned short)(uu[j] >> 16))     * Wcol[q * 8 + 2 * j + 1];
                }
            }
        } else {
            const float4* xr = (const float4*)((const float*)xin + (size_t)n * 64);
            #pragma unroll
            for (int q = 0; q < 16; q++) {
                float4 u = xr[q];
                acc += u.x * Wcol[4 * q]     + u.y * Wcol[4 * q + 1]
                     + u.z * Wcol[4 * q + 2] + u.w * Wcol[4 * q + 3];
            }
        }
        h[(size_t)n * 64 + lane] = f2bf(acc);
        float ps = acc * asl, pd = acc * adl;
        #pragma unroll
        for (int off = 32; off; off >>= 1) {
            ps += __shfl_xor(ps, off);
            pd += __shfl_xor(pd, off);
        }
        if (lane == 0) { hs[n] = ps; hd[n] = pd; }
    }
}

// ---------------- fused per-node GAT.
// R11: REVERT to the R2 structure (empirically best: 112us vs R4's 142us).
// R4's full h-LDS staging cost 50KB LDS -> occupancy 38->29.7% and moved the
// gather latency into a low-TLP pass-1 burst: net regression. Here:
//  - pass 1 (lane=edge): stage ea row -> eal (16KB), {att,src} -> arx (2KB);
//    ee recomputed inline from the staged row (int2 recs).
//  - softmax: 1 exp/lane + two shuffle reductions; att written to LDS.
//  - pass 2: 4 edges/iter (16 lanes each, 4 ch/lane), ea+att from LDS,
//    h[src] global gather at prefetch distance 1 (prologue load hoisted
//    above the reductions), paired-k v_pk_fma with pre-packed W.
// deg>64 (P~1e-7) falls back to a recompute-everything loop.
template<int L2>   // L2: selects wae half; fp32 output
__global__ __launch_bounds__(256, 3) void k_gat(const int2* __restrict__ recs,
                                                const int* __restrict__ offsets,
                                                const int* __restrict__ counts,
                                                const float* __restrict__ hs,
                                                const float* __restrict__ hd,
                                                const unsigned short* __restrict__ h,
                                                const float* __restrict__ ea,
                                                const float* __restrict__ wae,
                                                const float* __restrict__ We,
                                                const float* __restrict__ b,
                                                void* __restrict__ outv) {
    __shared__ float4 eal[4][4][64];   // [wave][k-quad][edge] : staged ea rows
    __shared__ float2 arx[4][64];      // [wave][edge] : {att, src-bits}
    int t = threadIdx.x, lane = t & 63, wv = t >> 6;
    int g = lane >> 4, cl = lane & 15;

    // W packed as k-pairs for the lane's 4 channels
    vf2 Wp[32];
    #pragma unroll
    for (int kp = 0; kp < 8; kp++) {
        float4 wa = *(const float4*)(We + (2 * kp) * 64 + 4 * cl);
        float4 wb = *(const float4*)(We + (2 * kp + 1) * 64 + 4 * cl);
        Wp[kp].x      = wa.x; Wp[kp].y      = wb.x;
        Wp[8 + kp].x  = wa.y; Wp[8 + kp].y  = wb.y;
        Wp[16 + kp].x = wa.z; Wp[16 + kp].y = wb.z;
        Wp[24 + kp].x = wa.w; Wp[24 + kp].y = wb.w;
    }
    // wae for this layer (broadcast loads; dead after pass 1)
    float waer[16];
    {
        const float4* wp4 = (const float4*)(wae + L2 * 16);
        float4 w0 = wp4[0], w1 = wp4[1], w2 = wp4[2], w3 = wp4[3];
        waer[0]=w0.x; waer[1]=w0.y; waer[2]=w0.z; waer[3]=w0.w;
        waer[4]=w1.x; waer[5]=w1.y; waer[6]=w1.z; waer[7]=w1.w;
        waer[8]=w2.x; waer[9]=w2.y; waer[10]=w2.z; waer[11]=w2.w;
        waer[12]=w3.x; waer[13]=w3.y; waer[14]=w3.z; waer[15]=w3.w;
    }

    int d = blockIdx.x * 4 + wv;           // grid is exactly NN/4
    int start = offsets[d];
    int deg = counts[d];

    if (deg == 0) {                        // isfinite -> 0, then bias + act
        if (g == 0) {
            float4 bl = *(const float4*)(b + 4 * cl);
            float o0 = (bl.x >= 0.f) ? bl.x : 0.01f * bl.x;
            float o1 = (bl.y >= 0.f) ? bl.y : 0.01f * bl.y;
            float o2 = (bl.z >= 0.f) ? bl.z : 0.01f * bl.z;
            float o3 = (bl.w >= 0.f) ? bl.w : 0.01f * bl.w;
            size_t oidx = (size_t)d * D + 4 * cl;
            if (L2) *(float4*)((float*)outv + oidx) = make_float4(o0, o1, o2, o3);
            else {
                ushort4 ov = {f2bf(o0), f2bf(o1), f2bf(o2), f2bf(o3)};
                *(ushort4*)((unsigned short*)outv + oidx) = ov;
            }
        }
        return;
    }

    float hdv = hd[d];
    bool fast = (deg <= 64);               // wave-uniform
    float m, invs;

    float ninf = -__builtin_inff();
    float a0 = ninf, a1 = ninf, a2 = ninf, a3 = ninf;

    if (fast) {
        // ---- pass 1: lane = edge; stage ea row + src, compute logit (ee inline).
        float lg = ninf;
        if (lane < deg) {
            int2 r = recs[start + lane];
            const float4* ep = (const float4*)(ea + (size_t)r.y * DE);
            float4 q0 = ep[0], q1 = ep[1], q2 = ep[2], q3 = ep[3];
            float hsv = hs[r.x];
            eal[wv][0][lane] = q0; eal[wv][1][lane] = q1;
            eal[wv][2][lane] = q2; eal[wv][3][lane] = q3;
            arx[wv][lane].y = __int_as_float(r.x);
            float ev[16] = {q0.x, q0.y, q0.z, q0.w, q1.x, q1.y, q1.z, q1.w,
                            q2.x, q2.y, q2.z, q2.w, q3.x, q3.y, q3.z, q3.w};
            float ee = 0.f;
            #pragma unroll
            for (int j = 0; j < 16; j++) ee += ev[j] * waer[j];
            lg = hsv + hdv + ee;
            lg = (lg >= 0.f) ? lg : 0.2f * lg;
        }

        // prologue h prefetch (needs only src; overlaps the reductions below)
        bool vC = (g < deg);
        int jC = vC ? g : 0;
        int rxC = __float_as_int(arx[wv][jC].y);
        ushort4 hvC = *(const ushort4*)(h + (size_t)rxC * D + 4 * cl);

        // ---- softmax: max-reduce, one exp/lane, sum-reduce
        m = lg;
        #pragma unroll
        for (int off = 32; off; off >>= 1) m = fmaxf(m, __shfl_xor(m, off));
        float p = __expf(lg - m);          // lanes >= deg: lg=-inf -> p=0
        float s = p;
        #pragma unroll
        for (int off = 32; off; off >>= 1) s += __shfl_xor(s, off);
        invs = 1.0f / fmaxf(s, 1e-16f);
        if (lane < deg) arx[wv][lane].x = p * invs;   // final att into LDS

        float attC = arx[wv][jC].x;        // after the .x writes (same wave)

        // ---- pass 2: 4 edges/iter; ea + att from LDS; h global prefetch d1.
        for (int i = 0; i < deg; i += 4) {
            int jn = i + 4 + g;
            bool vN = (jn < deg);
            int jN = vN ? jn : 0;
            float2 arN = arx[wv][jN];
            int rxN = __float_as_int(arN.y);
            ushort4 hvN = *(const ushort4*)(h + (size_t)rxN * D + 4 * cl);

            vf2 acA = {0.f, 0.f}, acB = {0.f, 0.f}, acC2 = {0.f, 0.f}, acD = {0.f, 0.f};
            #pragma unroll
            for (int kq = 0; kq < 4; kq++) {
                float4 q = eal[wv][kq][jC];
                vf2 eA; eA.x = q.x; eA.y = q.y;      // k-pair 2kq (packed from load)
                vf2 eB; eB.x = q.z; eB.y = q.w;      // k-pair 2kq+1
                acA += eA * Wp[2 * kq];       acA += eB * Wp[2 * kq + 1];
                acB += eA * Wp[8 + 2 * kq];   acB += eB * Wp[8 + 2 * kq + 1];
                acC2 += eA * Wp[16 + 2 * kq]; acC2 += eB * Wp[16 + 2 * kq + 1];
                acD += eA * Wp[24 + 2 * kq];  acD += eB * Wp[24 + 2 * kq + 1];
            }
            float e0 = acA.x + acA.y, e1 = acB.x + acB.y;
            float e2 = acC2.x + acC2.y, e3 = acD.x + acD.y;
            float o0 = (bf2f(hvC.x) + e0) * attC;
            float o1 = (bf2f(hvC.y) + e1) * attC;
            float o2 = (bf2f(hvC.z) + e2) * attC;
            float o3 = (bf2f(hvC.w) + e3) * attC;
            if (vC) {
                a0 = fmaxf(a0, o0); a1 = fmaxf(a1, o1);
                a2 = fmaxf(a2, o2); a3 = fmaxf(a3, o3);
            }
            // rotate pipeline
            attC = arN.x; hvC = hvN; vC = vN; jC = jN;
        }
    } else {
        // ---- slow path (deg > 64): online softmax + recompute-everything loop
        float mm = ninf, s = 0.f;
        for (int i = lane; i < deg; i += 64) {
            int2 r = recs[start + i];
            const float4* ep = (const float4*)(ea + (size_t)r.y * DE);
            float4 q0 = ep[0], q1 = ep[1], q2 = ep[2], q3 = ep[3];
            float ev[16] = {q0.x, q0.y, q0.z, q0.w, q1.x, q1.y, q1.z, q1.w,
                            q2.x, q2.y, q2.z, q2.w, q3.x, q3.y, q3.z, q3.w};
            float ee = 0.f;
            #pragma unroll
            for (int j = 0; j < 16; j++) ee += ev[j] * waer[j];
            float lg = hs[r.x] + hdv + ee;
            lg = (lg >= 0.f) ? lg : 0.2f * lg;
            float mn = fmaxf(mm, lg);
            s = ((mm == mn) ? s : s * __expf(mm - mn)) + __expf(lg - mn);
            mm = mn;
        }
        #pragma unroll
        for (int off = 32; off; off >>= 1) {
            float m2 = __shfl_xor(mm, off);
            float s2 = __shfl_xor(s, off);
            float mn = fmaxf(mm, m2);
            float sa = (mm == mn) ? s : s * __expf(mm - mn);
            float sb = (m2 == mn) ? s2 : s2 * __expf(m2 - mn);
            s = sa + sb;
            mm = mn;
        }
        m = mm;
        invs = 1.0f / fmaxf(s, 1e-16f);

        for (int i = 0; i < deg; i += 4) {
            int j = i + g;
            bool valid = (j < deg);
            int jc = valid ? j : 0;
            int2 r = recs[start + jc];
            const float4* ep = (const float4*)(ea + (size_t)r.y * DE);
            float4 q0 = ep[0], q1 = ep[1], q2 = ep[2], q3 = ep[3];
            float ev[16] = {q0.x, q0.y, q0.z, q0.w, q1.x, q1.y, q1.z, q1.w,
                            q2.x, q2.y, q2.z, q2.w, q3.x, q3.y, q3.z, q3.w};
            float ee = 0.f;
            #pragma unroll
            for (int j2 = 0; j2 < 16; j2++) ee += ev[j2] * waer[j2];
            float lg = hs[r.x] + hdv + ee;
            lg = (lg >= 0.f) ? lg : 0.2f * lg;
            float att = __expf(lg - m) * invs;
            ushort4 hv = *(const ushort4*)(h + (size_t)r.x * D + 4 * cl);
            float4 qs[4] = {q0, q1, q2, q3};
            vf2 acA = {0.f, 0.f}, acB = {0.f, 0.f}, acC2 = {0.f, 0.f}, acD = {0.f, 0.f};
            #pragma unroll
            for (int kq = 0; kq < 4; kq++) {
                float4 q = qs[kq];
                vf2 eA; eA.x = q.x; eA.y = q.y;
                vf2 eB; eB.x = q.z; eB.y = q.w;
                acA += eA * Wp[2 * kq];       acA += eB * Wp[2 * kq + 1];
                acB += eA * Wp[8 + 2 * kq];   acB += eB * Wp[8 + 2 * kq + 1];
                acC2 += eA * Wp[16 + 2 * kq]; acC2 += eB * Wp[16 + 2 * kq + 1];
                acD += eA * Wp[24 + 2 * kq];  acD += eB * Wp[24 + 2 * kq + 1];
            }
            float e0 = acA.x + acA.y, e1 = acB.x + acB.y;
            float e2 = acC2.x + acC2.y, e3 = acD.x + acD.y;
            float o0 = (bf2f(hv.x) + e0) * att;
            float o1 = (bf2f(hv.y) + e1) * att;
            float o2 = (bf2f(hv.z) + e2) * att;
            float o3 = (bf2f(hv.w) + e3) * att;
            if (valid) {
                a0 = fmaxf(a0, o0); a1 = fmaxf(a1, o1);
                a2 = fmaxf(a2, o2); a3 = fmaxf(a3, o3);
            }
        }
    }

    // combine the 4 groups (xor lanes 16, 32)
    #pragma unroll
    for (int off = 16; off <= 32; off <<= 1) {
        a0 = fmaxf(a0, __shfl_xor(a0, off));
        a1 = fmaxf(a1, __shfl_xor(a1, off));
        a2 = fmaxf(a2, __shfl_xor(a2, off));
        a3 = fmaxf(a3, __shfl_xor(a3, off));
    }

    if (g == 0) {
        float4 bl = *(const float4*)(b + 4 * cl);
        float o0 = a0 + bl.x, o1 = a1 + bl.y;
        float o2 = a2 + bl.z, o3 = a3 + bl.w;
        o0 = (o0 >= 0.f) ? o0 : 0.01f * o0;
        o1 = (o1 >= 0.f) ? o1 : 0.01f * o1;
        o2 = (o2 >= 0.f) ? o2 : 0.01f * o2;
        o3 = (o3 >= 0.f) ? o3 : 0.01f * o3;
        size_t oidx = (size_t)d * D + 4 * cl;
        if (L2) {
            *(float4*)((float*)outv + oidx) = make_float4(o0, o1, o2, o3);
        } else {
            ushort4 ov = {f2bf(o0), f2bf(o1), f2bf(o2), f2bf(o3)};
            *(ushort4*)((unsigned short*)outv + oidx) = ov;
        }
    }
}

extern "C" void kernel_launch(void* const* d_in, const int* in_sizes, int n_in,
                              void* d_out, int out_size, void* d_ws, size_t ws_size,
                              hipStream_t stream) {
    const float* X   = (const float*)d_in[0];
    const int*   eix = (const int*)d_in[1];
    const float* ea  = (const float*)d_in[2];
    const float* W1  = (const float*)d_in[3];
    const float* We1 = (const float*)d_in[4];
    const float* as1 = (const float*)d_in[5];
    const float* ad1 = (const float*)d_in[6];
    const float* ae1 = (const float*)d_in[7];
    const float* b1  = (const float*)d_in[8];
    const float* W2  = (const float*)d_in[9];
    const float* We2 = (const float*)d_in[10];
    const float* as2 = (const float*)d_in[11];
    const float* ad2 = (const float*)d_in[12];
    const float* ae2 = (const float*)d_in[13];
    const float* b2  = (const float*)d_in[14];

    const int* src = eix;
    const int* dst = eix + EE;

    // workspace carve — total ~26.8 MB
    char* w = (char*)d_ws;
    int2* recs = (int2*)w;               w += (size_t)EE * 8;          // 12.8 MB
    unsigned short* hA = (unsigned short*)w; w += (size_t)NN * D * 2;  // 6.4 MB (h1)
    unsigned short* hB = (unsigned short*)w; w += (size_t)NN * D * 2;  // 6.4 MB (c1 -> h2 in-place)
    float* hs = (float*)w;               w += (size_t)NN * 4;
    float* hd = (float*)w;               w += (size_t)NN * 4;
    int* counts = (int*)w;               w += (size_t)NN * 4;
    int* offsets = (int*)w;              w += (size_t)NN * 4;
    int* cursor = (int*)w;               w += (size_t)NN * 4;
    int* bsum = (int*)w;                 w += 256 * 4;
    float* wae = (float*)w;              w += 32 * 4;

    const int nchunks = (NN + 255) / 256;   // 196
    const int nhblk = (EE + 256 * HI_ILP - 1) / (256 * HI_ILP);   // 1563
    const int nsblk = (EE + 256 * SC_ILP - 1) / (256 * SC_ILP);   // 782

    hipMemsetAsync(counts, 0, (size_t)NN * 4, stream);
    k_hist<<<nhblk, 256, 0, stream>>>(dst, counts);
    k_scanA<<<nchunks, 256, 0, stream>>>(counts, bsum);
    k_scanB<<<1, 256, 0, stream>>>(bsum, nchunks, We1, ae1, We2, ae2, wae);
    k_scanC<<<nchunks, 256, 0, stream>>>(counts, bsum, offsets, cursor);
    k_scatter<<<nsblk, 256, 0, stream>>>(src, dst, cursor, recs);

    // layer 1
    k_gemm<0><<<1024, 256, 0, stream>>>(X, W1, as1, ad1, hA, hs, hd);
    k_gat<0><<<NN / 4, 256, 0, stream>>>(recs, offsets, counts, hs, hd, hA, ea,
                                         wae, We1, b1, hB);
    // layer 2
    k_gemm<1><<<1024, 256, 0, stream>>>(hB, W2, as2, ad2, hB, hs, hd);   // in-place
    k_gat<1><<<NN / 4, 256, 0, stream>>>(recs, offsets, counts, hs, hd, hB, ea,
                                         wae, We2, b2, (float*)d_out);
}